// Round 9
// baseline (173.405 us; speedup 1.0000x reference)
//
#include <hip/hip_runtime.h>
#include <hip/hip_bf16.h>

#define NB 16
#define NN 512
#define NH 8
#define NF 128
#define NEG_SLOPE 0.2f

typedef short bf16x8 __attribute__((ext_vector_type(8)));
typedef unsigned short u16x8 __attribute__((ext_vector_type(8)));
typedef float f32x4 __attribute__((ext_vector_type(4)));

__device__ inline unsigned short f2bf(float x) {
    __hip_bfloat16 b = __float2bfloat16(x);          // RNE hardware convert
    return __builtin_bit_cast(unsigned short, b);
}
__device__ inline float bf2f(unsigned short u) {
    return __uint_as_float(((unsigned int)u) << 16);
}

// ---------------- prep: emb=exp(bias) bf16, hT transpose (hi), wt hi/lo transpose, wa ----------------
// grid 1100 blocks x 256 thr:
//   [0,1024)    emb: 262144 elements
//   [1024,1088) hT[b][k][n] bf16 (LDS-tiled transpose, coalesced both sides)
//   [1088,1096) wt[h*128+f][k] hi/lo (LDS-tiled transpose)
//   [1096,1100) wa vectors
__global__ __launch_bounds__(256) void prep_kernel(
    const float* __restrict__ h, const int* __restrict__ adj,
    const float* __restrict__ bias, const float* __restrict__ W,
    const float* __restrict__ a,
    unsigned short* __restrict__ emb, unsigned short* __restrict__ hT,
    unsigned short* __restrict__ wtHi, unsigned short* __restrict__ wtLo,
    float* __restrict__ wasrc, float* __restrict__ wadst)
{
    __shared__ unsigned short lds[2][128][136];   // 69.6 KB
    int bx = blockIdx.x, tid = threadIdx.x;
    if (bx < 1024) {
        int t = bx * 256 + tid;
        emb[t] = (adj[t] != 0) ? f2bf(__expf(bias[t])) : (unsigned short)0;
    } else if (bx < 1088) {
        int bi = bx - 1024;
        int b = bi >> 2, nq = bi & 3;             // 128-row n-slab of batch b
        #pragma unroll 4
        for (int e = 0; e < 64; ++e) {
            int idx = e * 256 + tid;
            int nl = idx >> 7, f = idx & 127;
            float v = h[((size_t)(b * NN) + nq * 128 + nl) * NF + f];
            lds[0][f][nl] = f2bf(v);
        }
        __syncthreads();
        int k = tid >> 1, nh2 = tid & 1;
        #pragma unroll
        for (int u = 0; u < 8; ++u) {
            *(u16x8*)&hT[((size_t)(b * NF) + k) * NN + nq * 128 + nh2 * 64 + u * 8] =
                *(const u16x8*)&lds[0][k][nh2 * 64 + u * 8];
        }
    } else if (bx < 1096) {
        int h8 = bx - 1088;
        #pragma unroll 4
        for (int e = 0; e < 64; ++e) {
            int idx = e * 256 + tid;
            int k = idx >> 7, f = idx & 127;
            float v = W[((size_t)(h8 * NF) + k) * NF + f];
            unsigned short hi = f2bf(v);
            lds[0][f][k] = hi;
            lds[1][f][k] = f2bf(v - bf2f(hi));
        }
        __syncthreads();
        int f = tid >> 1, kh = tid & 1;
        #pragma unroll
        for (int u = 0; u < 8; ++u) {
            int off = kh * 64 + u * 8;
            size_t go = ((size_t)(h8 * NF) + f) * NF + off;
            *(u16x8*)&wtHi[go] = *(const u16x8*)&lds[0][f][off];
            *(u16x8*)&wtLo[go] = *(const u16x8*)&lds[1][f][off];
        }
    } else {
        int t = (bx - 1096) * 256 + tid;          // < 1024 = NH*NF
        int hh = t >> 7, i = t & 127;
        const float4* wrow = (const float4*)(W + (hh * NF + i) * NF);
        const float4* asr = (const float4*)(a + hh * 2 * NF);
        const float4* ads = (const float4*)(a + hh * 2 * NF + NF);
        float s1 = 0.f, s2 = 0.f;
        #pragma unroll 8
        for (int f = 0; f < NF / 4; ++f) {
            float4 w = wrow[f], x = asr[f], y = ads[f];
            s1 += w.x * x.x + w.y * x.y + w.z * x.z + w.w * x.w;
            s2 += w.x * y.x + w.y * y.y + w.z * y.z + w.w * y.w;
        }
        wasrc[t] = s1; wadst[t] = s2;
    }
}

// ---------------- scores: f32-exact; sdst stored transposed [b][h][n] ----------------
__global__ __launch_bounds__(256) void score_kernel(
    const float* __restrict__ h, const float* __restrict__ wasrc,
    const float* __restrict__ wadst, float* __restrict__ ssrc, float* __restrict__ sdstT)
{
    __shared__ float wsm[2][NH * (NF + 4)];
    int tid = threadIdx.x;
    for (int u = tid; u < NH * NF; u += 256) {
        int hh = u >> 7, f = u & 127;
        wsm[0][hh * (NF + 4) + f] = wasrc[u];
        wsm[1][hh * (NF + 4) + f] = wadst[u];
    }
    __syncthreads();
    int t = blockIdx.x * 256 + tid;           // over B*N*H
    int hh = t & 7;
    int bn = t >> 3;
    int b = bn >> 9, n = bn & 511;
    const float4* hrow = (const float4*)(h + (size_t)bn * NF);
    const float4* w1 = (const float4*)(&wsm[0][hh * (NF + 4)]);
    const float4* w2 = (const float4*)(&wsm[1][hh * (NF + 4)]);
    float s1 = 0.f, s2 = 0.f;
    #pragma unroll
    for (int u = 0; u < NF / 4; ++u) {
        float4 hv = hrow[u], a1 = w1[u], a2 = w2[u];
        s1 += hv.x * a1.x + hv.y * a1.y + hv.z * a1.z + hv.w * a1.w;
        s2 += hv.x * a2.x + hv.y * a2.y + hv.z * a2.z + hv.w * a2.w;
    }
    ssrc[t] = s1;
    sdstT[((size_t)(b * NH + hh)) * NN + n] = s2;
}

// ---------------- A-fragment compute: 8 e-values -> bf16, fully in-lane ----------------
__device__ inline bf16x8 make_afrag(float s, float4 v0, float4 v1, bf16x8 eb) {
    u16x8 ebu = __builtin_bit_cast(u16x8, eb);
    u16x8 r;
    float x;
    x = s + v0.x; x = fmaxf(x, NEG_SLOPE * x); r[0] = f2bf(__expf(x) * bf2f(ebu[0]));
    x = s + v0.y; x = fmaxf(x, NEG_SLOPE * x); r[1] = f2bf(__expf(x) * bf2f(ebu[1]));
    x = s + v0.z; x = fmaxf(x, NEG_SLOPE * x); r[2] = f2bf(__expf(x) * bf2f(ebu[2]));
    x = s + v0.w; x = fmaxf(x, NEG_SLOPE * x); r[3] = f2bf(__expf(x) * bf2f(ebu[3]));
    x = s + v1.x; x = fmaxf(x, NEG_SLOPE * x); r[4] = f2bf(__expf(x) * bf2f(ebu[4]));
    x = s + v1.y; x = fmaxf(x, NEG_SLOPE * x); r[5] = f2bf(__expf(x) * bf2f(ebu[5]));
    x = s + v1.z; x = fmaxf(x, NEG_SLOPE * x); r[6] = f2bf(__expf(x) * bf2f(ebu[6]));
    x = s + v1.w; x = fmaxf(x, NEG_SLOPE * x); r[7] = f2bf(__expf(x) * bf2f(ebu[7]));
    return __builtin_bit_cast(bf16x8, r);
}

// ---------------- attn v5: G = P.h via MFMA, then G.W_h in-kernel, head-mean ----------------
// grid 512: bx = it*16 + b (bx%8 = b%8 -> hT[b] XCD-local). 512 thr = 8 waves = 8 heads.
// Wave: C_G[16 i][128 k] over j=512 (phase A), LDS transpose, C2[16 i][128 f] (phase B).
__global__ __launch_bounds__(512, 4) void attn_kernel(
    const unsigned short* __restrict__ hT, const unsigned short* __restrict__ emb,
    const float* __restrict__ ssrc, const float* __restrict__ sdstT,
    const unsigned short* __restrict__ wtHi, const unsigned short* __restrict__ wtLo,
    float* __restrict__ out)
{
    __shared__ float red[NH][16][136];        // 69.6 KB -> 2 blocks/CU
    int bx = blockIdx.x;
    int b = bx & 15;
    int it = bx >> 4;                         // 0..31
    int i0 = it * 16;
    int tid = threadIdx.x;
    int lane = tid & 63, hh = tid >> 6;
    int col = lane & 15, kg = lane >> 4;

    const short one_bf = (short)0x3f80;
    const bf16x8 vone = {one_bf, one_bf, one_bf, one_bf, one_bf, one_bf, one_bf, one_bf};

    const float* sd = sdstT + (size_t)(b * NH + hh) * NN;
    float s0 = ssrc[((size_t)(b * NN) + i0 + col) * NH + hh];
    const unsigned short* ebp = emb + (size_t)(i0 + col) * NN;
    const unsigned short* Bb = hT + ((size_t)(b * NF) + col) * NN;   // + tk*16*NN + j

    f32x4 acc[8];
    f32x4 accS = {0.f, 0.f, 0.f, 0.f};
    #pragma unroll
    for (int q = 0; q < 8; ++q) acc[q] = (f32x4){0.f, 0.f, 0.f, 0.f};

    // ---- phase A: G = P.h, ping-ponged loads, zero barriers ----
    float4 svA0 = *(const float4*)(sd + kg * 8);
    float4 svA1 = *(const float4*)(sd + kg * 8 + 4);
    bf16x8 ebA = *(const bf16x8*)(ebp + kg * 8);
    bf16x8 Ba[4];
    #pragma unroll
    for (int q = 0; q < 4; ++q)
        Ba[q] = *(const bf16x8*)(Bb + (size_t)(q * 16) * NN + kg * 8);

    float4 svB0, svB1; bf16x8 ebB;
    #pragma unroll
    for (int t = 0; t < 16; ++t) {
        int jc = t * 32 + kg * 8;
        bf16x8 Bhi[4];
        #pragma unroll
        for (int q = 0; q < 4; ++q)
            Bhi[q] = *(const bf16x8*)(Bb + (size_t)((4 + q) * 16) * NN + jc);
        if (t < 15) {
            svB0 = *(const float4*)(sd + jc + 32);
            svB1 = *(const float4*)(sd + jc + 36);
            ebB  = *(const bf16x8*)(ebp + jc + 32);
        }
        bf16x8 A = make_afrag(s0, svA0, svA1, ebA);
        __builtin_amdgcn_s_setprio(1);
        accS = __builtin_amdgcn_mfma_f32_16x16x32_bf16(A, vone, accS, 0, 0, 0);
        #pragma unroll
        for (int q = 0; q < 4; ++q)
            acc[q] = __builtin_amdgcn_mfma_f32_16x16x32_bf16(A, Ba[q], acc[q], 0, 0, 0);
        __builtin_amdgcn_s_setprio(0);
        if (t < 15) {
            #pragma unroll
            for (int q = 0; q < 4; ++q)
                Ba[q] = *(const bf16x8*)(Bb + (size_t)(q * 16) * NN + jc + 32);
        }
        __builtin_amdgcn_s_setprio(1);
        #pragma unroll
        for (int q = 0; q < 4; ++q)
            acc[4 + q] = __builtin_amdgcn_mfma_f32_16x16x32_bf16(A, Bhi[q], acc[4 + q], 0, 0, 0);
        __builtin_amdgcn_s_setprio(0);
        if (t < 15) { svA0 = svB0; svA1 = svB1; ebA = ebB; }
    }

    // ---- normalize G and stage in LDS (f32): G[i=kg*4+r][k=tk*16+col] ----
    f32x4 rinv;
    #pragma unroll
    for (int r = 0; r < 4; ++r) rinv[r] = 1.0f / accS[r];
    #pragma unroll
    for (int tk = 0; tk < 8; ++tk)
        #pragma unroll
        for (int r = 0; r < 4; ++r)
            red[hh][kg * 4 + r][tk * 16 + col] = acc[tk][r] * rinv[r];

    // ---- rebuild A-frags from own head's G (in-wave, DS in-order) ----
    bf16x8 af[4];
    #pragma unroll
    for (int ks = 0; ks < 4; ++ks) {
        float4 g0 = *(const float4*)&red[hh][col][ks * 32 + kg * 8];
        float4 g1 = *(const float4*)&red[hh][col][ks * 32 + kg * 8 + 4];
        u16x8 tmp;
        tmp[0] = f2bf(g0.x); tmp[1] = f2bf(g0.y); tmp[2] = f2bf(g0.z); tmp[3] = f2bf(g0.w);
        tmp[4] = f2bf(g1.x); tmp[5] = f2bf(g1.y); tmp[6] = f2bf(g1.z); tmp[7] = f2bf(g1.w);
        af[ks] = __builtin_bit_cast(bf16x8, tmp);
    }

    // ---- phase B: C2[16 i][128 f] = G . W_h (hi+lo) ----
    f32x4 acc2[8];
    #pragma unroll
    for (int q = 0; q < 8; ++q) acc2[q] = (f32x4){0.f, 0.f, 0.f, 0.f};
    const unsigned short* wh = wtHi + ((size_t)(hh * NF) + col) * NF + kg * 8;
    const unsigned short* wl = wtLo + ((size_t)(hh * NF) + col) * NF + kg * 8;
    #pragma unroll
    for (int ft = 0; ft < 8; ++ft) {
        #pragma unroll
        for (int ks = 0; ks < 4; ++ks) {
            bf16x8 bhv = *(const bf16x8*)(wh + (size_t)(ft * 16) * NF + ks * 32);
            bf16x8 blv = *(const bf16x8*)(wl + (size_t)(ft * 16) * NF + ks * 32);
            acc2[ft] = __builtin_amdgcn_mfma_f32_16x16x32_bf16(af[ks], bhv, acc2[ft], 0, 0, 0);
            acc2[ft] = __builtin_amdgcn_mfma_f32_16x16x32_bf16(af[ks], blv, acc2[ft], 0, 0, 0);
        }
    }

    // ---- overwrite own region with C2, then head-mean ----
    #pragma unroll
    for (int ft = 0; ft < 8; ++ft)
        #pragma unroll
        for (int r = 0; r < 4; ++r)
            red[hh][kg * 4 + r][ft * 16 + col] = acc2[ft][r];
    __syncthreads();

    int i = tid >> 5;
    int fq = (tid & 31) * 4;
    float4 s = {0.f, 0.f, 0.f, 0.f};
    #pragma unroll
    for (int w = 0; w < NH; ++w) {
        float4 v = *(const float4*)&red[w][i][fq];
        s.x += v.x; s.y += v.y; s.z += v.z; s.w += v.w;
    }
    s.x *= 0.125f; s.y *= 0.125f; s.z *= 0.125f; s.w *= 0.125f;
    *(float4*)&out[((size_t)(b * NN) + i0 + i) * NF + fq] = s;
}

extern "C" void kernel_launch(void* const* d_in, const int* in_sizes, int n_in,
                              void* d_out, int out_size, void* d_ws, size_t ws_size,
                              hipStream_t stream)
{
    const float* h    = (const float*)d_in[0];
    const int*   adj  = (const int*)d_in[1];
    const float* bias = (const float*)d_in[2];
    const float* W    = (const float*)d_in[3];
    const float* a    = (const float*)d_in[4];
    float* out = (float*)d_out;

    char* ws = (char*)d_ws;
    unsigned short* hT   = (unsigned short*)ws;   ws += (size_t)NB * NF * NN * 2;        // 2 MB
    unsigned short* emb  = (unsigned short*)ws;   ws += (size_t)NN * NN * 2;             // 0.5 MB
    unsigned short* wtHi = (unsigned short*)ws;   ws += (size_t)NH * NF * NF * 2;        // 0.25 MB
    unsigned short* wtLo = (unsigned short*)ws;   ws += (size_t)NH * NF * NF * 2;
    float* ssrc  = (float*)ws;                    ws += (size_t)NB * NN * NH * 4;
    float* sdstT = (float*)ws;                    ws += (size_t)NB * NN * NH * 4;
    float* wasrc = (float*)ws;                    ws += NH * NF * 4;
    float* wadst = (float*)ws;                    ws += NH * NF * 4;

    hipLaunchKernelGGL(prep_kernel, dim3(1100), dim3(256), 0, stream,
                       h, adj, bias, W, a, emb, hT, wtHi, wtLo, wasrc, wadst);
    hipLaunchKernelGGL(score_kernel, dim3((NB * NN * NH) / 256), dim3(256), 0, stream,
                       h, wasrc, wadst, ssrc, sdstT);
    hipLaunchKernelGGL(attn_kernel, dim3(NB * 32), dim3(512), 0, stream,
                       hT, emb, ssrc, sdstT, wtHi, wtLo, out);
}